// Round 12
// baseline (231.651 us; speedup 1.0000x reference)
//
#include <hip/hip_runtime.h>
#include <stdint.h>

#define SEQ 2048
#define BSZ 4
#define NH 16
#define HD 64
#define EMB 1024
#define NT (SEQ / 64)
#define QSCALE 0.1803368801111f   // 0.125 * log2(e)

using bf16x8 = __attribute__((ext_vector_type(8))) __bf16;
using u16x8  = __attribute__((ext_vector_type(8))) unsigned short;
using u32x4  = __attribute__((ext_vector_type(4))) uint32_t;
using f32x4  = __attribute__((ext_vector_type(4))) float;
using f32x16 = __attribute__((ext_vector_type(16))) float;

__device__ __forceinline__ float exp2v(float x) { return __builtin_amdgcn_exp2f(x); }

__device__ __forceinline__ unsigned short f2bf(float f) {
    union { float f; uint32_t u; } v; v.f = f;
    uint32_t r = v.u + 0x7fffu + ((v.u >> 16) & 1u);
    return (unsigned short)(r >> 16);
}

__device__ __forceinline__ uint32_t cvtpk(float lo, float hi) {
    uint32_t r;
    asm("v_cvt_pk_bf16_f32 %0, %1, %2" : "=v"(r) : "v"(lo), "v"(hi));
    return r;
}
__device__ __forceinline__ void plswap(uint32_t& a, uint32_t& b) {
    asm volatile("v_permlane32_swap_b32 %0, %1" : "+v"(a), "+v"(b));
}

// async global->LDS, 16B per lane; dest = wave-uniform base + lane*16
__device__ __forceinline__ void gload16(void* lds, const void* g) {
    __builtin_amdgcn_global_load_lds(
        (const __attribute__((address_space(1))) void*)g,
        (__attribute__((address_space(3))) void*)lds, 16, 0, 0);
}

// ---------------- cast fp32 -> bf16 ----------------
__global__ void cast_kernel(const float* __restrict__ s, unsigned short* __restrict__ d, int n) {
    int i = (blockIdx.x * blockDim.x + threadIdx.x) * 4;
    if (i + 3 >= n) {
        for (int j = 0; j < 4 && i + j < n; ++j) d[i + j] = f2bf(s[i + j]);
        return;
    }
    float4 v = *(const float4*)(s + i);
    ushort4 o;
    o.x = f2bf(v.x); o.y = f2bf(v.y); o.z = f2bf(v.z); o.w = f2bf(v.w);
    *(ushort4*)(d + i) = o;
}

// 4 weight matrices (1024x1024 each) in one launch; grid (1024, 4)
__global__ void cast4_kernel(const float* __restrict__ w0, const float* __restrict__ w1,
                             const float* __restrict__ w2, const float* __restrict__ w3,
                             unsigned short* __restrict__ d0, unsigned short* __restrict__ d1,
                             unsigned short* __restrict__ d2, unsigned short* __restrict__ d3) {
    const float* s; unsigned short* d;
    switch (blockIdx.y) {
        case 0:  s = w0; d = d0; break;
        case 1:  s = w1; d = d1; break;
        case 2:  s = w2; d = d2; break;
        default: s = w3; d = d3; break;
    }
    int i = (blockIdx.x * blockDim.x + threadIdx.x) * 4;
    float4 v = *(const float4*)(s + i);
    ushort4 o;
    o.x = f2bf(v.x); o.y = f2bf(v.y); o.z = f2bf(v.z); o.w = f2bf(v.w);
    *(ushort4*)(d + i) = o;
}

// ---------------- GEMM (m97 structure, round-10 proven) --------------------
// MODE 0: f32 out to C0 (bias b0).  MODE 2: QKV fused — n-seg 0 -> Q (scaled
// by QSCALE), 1 -> K, 2 -> V^T (transposed write [b,h,d,seq]).
template <int MODE>
__global__ __launch_bounds__(256, 2)
void gemm_bt(const unsigned short* __restrict__ A,
             const unsigned short* __restrict__ Bw,
             const float* __restrict__ b0, const float* __restrict__ b1,
             const float* __restrict__ b2,
             void* __restrict__ C0, void* __restrict__ C1, void* __restrict__ C2,
             int M, int N, int Kd) {
    __shared__ unsigned short As[128][64];
    __shared__ unsigned short Bs[128][64];

    const int t    = threadIdx.x;
    const int lane = t & 63;
    const int wid  = t >> 6;
    const int g    = lane >> 4;
    const int lr   = lane & 15;
    const int wm   = wid >> 1, wn = wid & 1;
    const int m0   = blockIdx.x * 128, n0 = blockIdx.y * 128;
    const int srow = lane >> 3;          // 0..7 within 8-row stripe
    const int scol = (lane & 7) * 8;     // shorts

    f32x4 acc[4][4];
    const f32x4 zero = {0.f, 0.f, 0.f, 0.f};
#pragma unroll
    for (int i = 0; i < 4; ++i)
#pragma unroll
        for (int j = 0; j < 4; ++j) acc[i][j] = zero;

    for (int kt = 0; kt < Kd; kt += 64) {
#pragma unroll
        for (int p = 0; p < 4; ++p) {
            int rowA = wid * 32 + p * 8;
            gload16(&As[rowA][0], A  + (size_t)(m0 + rowA + srow) * Kd + kt + scol);
            gload16(&Bs[rowA][0], Bw + (size_t)(n0 + rowA + srow) * Kd + kt + scol);
        }
        __syncthreads();   // compiler drains vmcnt before barrier
#pragma unroll
        for (int ks = 0; ks < 2; ++ks) {
            bf16x8 af[4], bfr[4];
#pragma unroll
            for (int m = 0; m < 4; ++m)
                af[m] = *(const bf16x8*)&As[wm * 64 + m * 16 + lr][ks * 32 + g * 8];
#pragma unroll
            for (int n = 0; n < 4; ++n)
                bfr[n] = *(const bf16x8*)&Bs[wn * 64 + n * 16 + lr][ks * 32 + g * 8];
#pragma unroll
            for (int m = 0; m < 4; ++m)
#pragma unroll
                for (int n = 0; n < 4; ++n)
                    acc[m][n] = __builtin_amdgcn_mfma_f32_16x16x32_bf16(af[m], bfr[n], acc[m][n], 0, 0, 0);
        }
        __syncthreads();
    }

    int seg = MODE == 2 ? (n0 >> 10) : 0;
    if (MODE == 2 && seg == 2) {
        // V^T write: [b*1024 + colL][seq], 4 consecutive seq per ushort4
        unsigned short* CwT = (unsigned short*)C2;
        int nl = n0 & 1023;
#pragma unroll
        for (int n = 0; n < 4; ++n) {
            int colL = nl + wn * 64 + n * 16 + lr;
            float bv = b2[colL];
#pragma unroll
            for (int m = 0; m < 4; ++m) {
                int rowg = m0 + wm * 64 + m * 16 + g * 4;
                int bb = rowg >> 11, seq = rowg & 2047;
                ushort4 w;
                w.x = f2bf(acc[m][n][0] + bv);
                w.y = f2bf(acc[m][n][1] + bv);
                w.z = f2bf(acc[m][n][2] + bv);
                w.w = f2bf(acc[m][n][3] + bv);
                *(ushort4*)(CwT + ((size_t)(bb * 1024 + colL)) * SEQ + seq) = w;
            }
        }
        return;
    }

    const float* bias;
    unsigned short* Cw = nullptr;
    float* Cf = nullptr;
    float scl = 1.0f;
    int nl;
    if (MODE == 2) {
        bias = seg == 0 ? b0 : b1;
        Cw = (unsigned short*)(seg == 0 ? C0 : C1);
        scl = seg == 0 ? QSCALE : 1.0f;
        nl = n0 & 1023;
    } else {
        bias = b0; Cf = (float*)C0; nl = n0;
    }
#pragma unroll
    for (int n = 0; n < 4; ++n) {
        int colL = nl + wn * 64 + n * 16 + lr;
        float bv = bias[colL];
#pragma unroll
        for (int m = 0; m < 4; ++m) {
            int rowg = m0 + wm * 64 + m * 16 + g * 4;
#pragma unroll
            for (int r = 0; r < 4; ++r) {
                float val = (acc[m][n][r] + bv) * scl;
                if (MODE == 2)
                    Cw[(size_t)(rowg + r) * EMB + colL] = f2bf(val);
                else
                    Cf[(size_t)(rowg + r) * EMB + colL] = val;
            }
        }
    }
}

// ---------------- Flash attention v10: 64 q-rows/wave ----------------------
// LDS-BW fix: each wave computes TWO 32-row q-sets from ONE K/V fragment
// read -> LDS read traffic per CU per tile halves. 4 waves / 256 threads,
// grid 512 blocks (XCD-swizzled). Round-8 softmax per q-set.
__global__ __launch_bounds__(256, 2)
void flash_attn(const unsigned short* __restrict__ Q,
                const unsigned short* __restrict__ K,
                const unsigned short* __restrict__ VT,
                unsigned short* __restrict__ O) {
    __shared__ unsigned char KsB[2][64 * 128];   // K[k][d],  XOR-16B swizzled
    __shared__ unsigned char VtB[2][64 * 128];   // V^T[d][k], XOR-16B swizzled

    // bijective XCD swizzle: 512 blocks, 8 XCDs, 64 consecutive per XCD
    const int nwg  = gridDim.x * gridDim.y * gridDim.z;
    const int cpx  = nwg >> 3;
    const int bid0 = (blockIdx.z * gridDim.y + blockIdx.y) * gridDim.x + blockIdx.x;
    const int bid  = (bid0 % 8) * cpx + (bid0 / 8);
    const int bx   = bid & (gridDim.x - 1);          // SEQ/256 = 8 (pow2)
    const int h    = (bid >> 3) & 15;
    const int b    = bid >> 7;

    const int t    = threadIdx.x;        // 0..255
    const int wid  = t >> 6;             // 0..3
    const int lane = t & 63;
    const int l31  = lane & 31;
    const int hi   = lane >> 5;
    const int hi16 = hi << 4;
    const int sw   = (l31 & 7) << 4;
    const int qb0  = bx * 256 + wid * 64;            // wave's 64 q-rows
    const size_t rowbase = (size_t)b * SEQ;
    const unsigned short* Kh  = K + rowbase * EMB + h * HD;
    const unsigned short* Vth = VT + (size_t)(b * 1024 + h * HD) * SEQ;

    bf16x8 qf[2][4];
#pragma unroll
    for (int qs = 0; qs < 2; ++qs)
#pragma unroll
        for (int db = 0; db < 4; ++db)
            qf[qs][db] = *(const bf16x8*)(Q + (rowbase + qb0 + qs * 32 + l31) * EMB
                                            + h * HD + db * 16 + hi * 8);

    bf16x8 vones;
#pragma unroll
    for (int j = 0; j < 8; ++j) vones[j] = (__bf16)1.0f;

    f32x16 oA0, oA1, oA2, oB0, oB1, oB2;
#pragma unroll
    for (int r = 0; r < 16; ++r) {
        oA0[r] = 0.f; oA1[r] = 0.f; oA2[r] = 0.f;
        oB0[r] = 0.f; oB1[r] = 0.f; oB2[r] = 0.f;
    }
    float meA = -1e30f, meB = -1e30f;

    // staging: 4 waves x 2 calls x 1KB = 8KB per tile (K and V each).
    auto issue_tile = [&](int kt) {
#pragma unroll
        for (int c = 0; c < 2; ++c) {
            int slot = (wid * 2 + c) * 64 + lane;
            int row  = slot >> 3;
            int c16  = (slot & 7) ^ (row & 7);       // XOR moved to source
            gload16(KsB[kt & 1] + (wid * 2 + c) * 1024,
                    Kh + (size_t)(kt * 64 + row) * EMB + c16 * 8);
            gload16(VtB[kt & 1] + (wid * 2 + c) * 1024,
                    Vth + (size_t)row * SEQ + (size_t)kt * 64 + c16 * 8);
        }
    };

    auto softmax_pack = [&](f32x16& s0, f32x16& s1, float& me,
                            f32x16& o0, f32x16& o1, f32x16& o2, bf16x8* pa) {
        float pm = fmaxf(fmaxf(s0[0], s0[1]), s0[2]);
#pragma unroll
        for (int r = 3; r < 15; r += 2) pm = fmaxf(fmaxf(pm, s0[r]), s0[r + 1]);
        pm = fmaxf(pm, s0[15]);
#pragma unroll
        for (int r = 0; r < 16; r += 2) pm = fmaxf(fmaxf(pm, s1[r]), s1[r + 1]);
        pm = fmaxf(pm, __shfl_xor(pm, 32));

        if (!__all(pm - me <= 8.0f)) {               // defer-max, THR=8
            float mn = fmaxf(me, pm);
            float al = exp2v(me - mn);
            me = mn;
#pragma unroll
            for (int r = 0; r < 16; ++r) {
                int addr = hi16 + (((r & 3) + 8 * (r >> 2)) << 2);
                float ar = __int_as_float(
                    __builtin_amdgcn_ds_bpermute(addr, __float_as_int(al)));
                o0[r] *= ar; o1[r] *= ar; o2[r] *= ar;
            }
        }
        s0 = s0 - me;
        s1 = s1 - me;
#pragma unroll
        for (int r = 0; r < 16; ++r) s0[r] = exp2v(s0[r]);
#pragma unroll
        for (int r = 0; r < 16; ++r) s1[r] = exp2v(s1[r]);
#pragma unroll
        for (int kb = 0; kb < 2; ++kb) {
            uint32_t dw[8];
#pragma unroll
            for (int i = 0; i < 8; ++i)
                dw[i] = kb == 0 ? cvtpk(s0[2 * i], s0[2 * i + 1])
                                : cvtpk(s1[2 * i], s1[2 * i + 1]);
            plswap(dw[0], dw[2]); plswap(dw[1], dw[3]);
            plswap(dw[4], dw[6]); plswap(dw[5], dw[7]);
            u32x4 w0 = {dw[0], dw[1], dw[2], dw[3]};
            u32x4 w1 = {dw[4], dw[5], dw[6], dw[7]};
            pa[kb * 2]     = __builtin_bit_cast(bf16x8, w0);
            pa[kb * 2 + 1] = __builtin_bit_cast(bf16x8, w1);
        }
    };

    issue_tile(0);

    for (int kt = 0; kt < NT; ++kt) {
        unsigned char* Ks = KsB[kt & 1];
        unsigned char* Vt = VtB[kt & 1];

        __syncthreads();                      // drains DMA for tile kt; prev reads done
        if (kt + 1 < NT) issue_tile(kt + 1);  // DMA next tile into other buffer

        // K fragments read ONCE, used by both q-sets
        bf16x8 kf[2][4];
#pragma unroll
        for (int db = 0; db < 4; ++db) {
            kf[0][db] = *(const bf16x8*)(Ks + l31 * 128        + ((db * 32 + hi16) ^ sw));
            kf[1][db] = *(const bf16x8*)(Ks + (l31 + 32) * 128 + ((db * 32 + hi16) ^ sw));
        }

        bf16x8 paA[4], paB[4];
        {
            f32x16 s0, s1;
#pragma unroll
            for (int r = 0; r < 16; ++r) { s0[r] = 0.f; s1[r] = 0.f; }
            __builtin_amdgcn_s_setprio(1);
#pragma unroll
            for (int db = 0; db < 4; ++db) {
                s0 = __builtin_amdgcn_mfma_f32_32x32x16_bf16(kf[0][db], qf[0][db], s0, 0, 0, 0);
                s1 = __builtin_amdgcn_mfma_f32_32x32x16_bf16(kf[1][db], qf[0][db], s1, 0, 0, 0);
            }
            __builtin_amdgcn_s_setprio(0);
            softmax_pack(s0, s1, meA, oA0, oA1, oA2, paA);
        }
        {
            f32x16 s0, s1;
#pragma unroll
            for (int r = 0; r < 16; ++r) { s0[r] = 0.f; s1[r] = 0.f; }
            __builtin_amdgcn_s_setprio(1);
#pragma unroll
            for (int db = 0; db < 4; ++db) {
                s0 = __builtin_amdgcn_mfma_f32_32x32x16_bf16(kf[0][db], qf[1][db], s0, 0, 0, 0);
                s1 = __builtin_amdgcn_mfma_f32_32x32x16_bf16(kf[1][db], qf[1][db], s1, 0, 0, 0);
            }
            __builtin_amdgcn_s_setprio(0);
            softmax_pack(s0, s1, meB, oB0, oB1, oB2, paB);
        }

        // V fragments read ONCE, PV for both q-sets
        __builtin_amdgcn_s_setprio(1);
#pragma unroll
        for (int kk = 0; kk < 4; ++kk) {
            bf16x8 vf0 = *(const bf16x8*)(Vt + l31 * 128        + ((kk * 32 + hi16) ^ sw));
            bf16x8 vf1 = *(const bf16x8*)(Vt + (l31 + 32) * 128 + ((kk * 32 + hi16) ^ sw));
            oA0 = __builtin_amdgcn_mfma_f32_32x32x16_bf16(paA[kk], vf0, oA0, 0, 0, 0);
            oA1 = __builtin_amdgcn_mfma_f32_32x32x16_bf16(paA[kk], vf1, oA1, 0, 0, 0);
            oA2 = __builtin_amdgcn_mfma_f32_32x32x16_bf16(paA[kk], vones, oA2, 0, 0, 0);
            oB0 = __builtin_amdgcn_mfma_f32_32x32x16_bf16(paB[kk], vf0, oB0, 0, 0, 0);
            oB1 = __builtin_amdgcn_mfma_f32_32x32x16_bf16(paB[kk], vf1, oB1, 0, 0, 0);
            oB2 = __builtin_amdgcn_mfma_f32_32x32x16_bf16(paB[kk], vones, oB2, 0, 0, 0);
        }
        __builtin_amdgcn_s_setprio(0);
    }

    // epilogue: o2[r] holds the softmax denominator for this lane's q-row
#pragma unroll
    for (int r = 0; r < 16; ++r) {
        int qoff = (r & 3) + 8 * (r >> 2) + 4 * hi;
        {
            float inv = 1.0f / oA2[r];
            size_t ro = (rowbase + qb0 + qoff) * EMB + h * HD;
            O[ro + l31]      = f2bf(oA0[r] * inv);
            O[ro + 32 + l31] = f2bf(oA1[r] * inv);
        }
        {
            float inv = 1.0f / oB2[r];
            size_t ro = (rowbase + qb0 + 32 + qoff) * EMB + h * HD;
            O[ro + l31]      = f2bf(oB0[r] * inv);
            O[ro + 32 + l31] = f2bf(oB1[r] * inv);
        }
    }
}

extern "C" void kernel_launch(void* const* d_in, const int* in_sizes, int n_in,
                              void* d_out, int out_size, void* d_ws, size_t ws_size,
                              hipStream_t stream) {
    const float* x  = (const float*)d_in[0];
    const float* wq = (const float*)d_in[1];
    const float* bq = (const float*)d_in[2];
    const float* wk = (const float*)d_in[3];
    const float* bk = (const float*)d_in[4];
    const float* wv = (const float*)d_in[5];
    const float* bv = (const float*)d_in[6];
    const float* wo = (const float*)d_in[7];
    const float* bo = (const float*)d_in[8];

    char* ws = (char*)d_ws;
    const size_t M = (size_t)BSZ * SEQ;              // 8192
    unsigned short* xb    = (unsigned short*)ws;                       // 16 MB, reused as attn out
    unsigned short* wqkvb = (unsigned short*)(ws + (size_t)16 * 1024 * 1024);  // 6 MB
    unsigned short* wob   = (unsigned short*)(ws + (size_t)22 * 1024 * 1024);  // 2 MB
    unsigned short* Qb    = (unsigned short*)(ws + (size_t)24 * 1024 * 1024);
    unsigned short* Kb    = Qb + M * EMB;
    unsigned short* VTb   = Kb + M * EMB;            // V^T [b*16+h][64][2048]

    const int nX = (int)(M * EMB);
    cast_kernel<<<nX / 1024, 256, 0, stream>>>(x, xb, nX);
    cast4_kernel<<<dim3(1024, 4), 256, 0, stream>>>(
        wq, wk, wv, wo,
        wqkvb, wqkvb + 1024 * 1024, wqkvb + 2 * 1024 * 1024, wob);

    gemm_bt<2><<<dim3(64, 24), 256, 0, stream>>>(xb, wqkvb, bq, bk, bv,
                                                 Qb, Kb, VTb, (int)M, 3 * EMB, EMB);

    flash_attn<<<dim3(SEQ / 256, NH, BSZ), 256, 0, stream>>>(Qb, Kb, VTb, xb);

    gemm_bt<0><<<dim3(64, 8), 256, 0, stream>>>(xb, wob, bo, nullptr, nullptr,
                                                d_out, nullptr, nullptr, (int)M, EMB, EMB);
}

// Round 13
// 201.262 us; speedup vs baseline: 1.1510x; 1.1510x over previous
//
#include <hip/hip_runtime.h>
#include <stdint.h>

#define SEQ 2048
#define BSZ 4
#define NH 16
#define HD 64
#define EMB 1024
#define NT (SEQ / 64)
#define QSCALE 0.1803368801111f   // 0.125 * log2(e)

using bf16x8 = __attribute__((ext_vector_type(8))) __bf16;
using u16x8  = __attribute__((ext_vector_type(8))) unsigned short;
using u32x4  = __attribute__((ext_vector_type(4))) uint32_t;
using f32x4  = __attribute__((ext_vector_type(4))) float;
using f32x16 = __attribute__((ext_vector_type(16))) float;

__device__ __forceinline__ float exp2v(float x) { return __builtin_amdgcn_exp2f(x); }

__device__ __forceinline__ unsigned short f2bf(float f) {
    union { float f; uint32_t u; } v; v.f = f;
    uint32_t r = v.u + 0x7fffu + ((v.u >> 16) & 1u);
    return (unsigned short)(r >> 16);
}

__device__ __forceinline__ uint32_t cvtpk(float lo, float hi) {
    uint32_t r;
    asm("v_cvt_pk_bf16_f32 %0, %1, %2" : "=v"(r) : "v"(lo), "v"(hi));
    return r;
}
__device__ __forceinline__ void plswap(uint32_t& a, uint32_t& b) {
    asm volatile("v_permlane32_swap_b32 %0, %1" : "+v"(a), "+v"(b));
}

// async global->LDS, 16B per lane; dest = wave-uniform base + lane*16
__device__ __forceinline__ void gload16(void* lds, const void* g) {
    __builtin_amdgcn_global_load_lds(
        (const __attribute__((address_space(1))) void*)g,
        (__attribute__((address_space(3))) void*)lds, 16, 0, 0);
}

// ---------------- cast fp32 -> bf16 ----------------
__global__ void cast_kernel(const float* __restrict__ s, unsigned short* __restrict__ d, int n) {
    int i = (blockIdx.x * blockDim.x + threadIdx.x) * 4;
    if (i + 3 >= n) {
        for (int j = 0; j < 4 && i + j < n; ++j) d[i + j] = f2bf(s[i + j]);
        return;
    }
    float4 v = *(const float4*)(s + i);
    ushort4 o;
    o.x = f2bf(v.x); o.y = f2bf(v.y); o.z = f2bf(v.z); o.w = f2bf(v.w);
    *(ushort4*)(d + i) = o;
}

// 4 weight matrices (1024x1024 each) in one launch; grid (1024, 4)
__global__ void cast4_kernel(const float* __restrict__ w0, const float* __restrict__ w1,
                             const float* __restrict__ w2, const float* __restrict__ w3,
                             unsigned short* __restrict__ d0, unsigned short* __restrict__ d1,
                             unsigned short* __restrict__ d2, unsigned short* __restrict__ d3) {
    const float* s; unsigned short* d;
    switch (blockIdx.y) {
        case 0:  s = w0; d = d0; break;
        case 1:  s = w1; d = d1; break;
        case 2:  s = w2; d = d2; break;
        default: s = w3; d = d3; break;
    }
    int i = (blockIdx.x * blockDim.x + threadIdx.x) * 4;
    float4 v = *(const float4*)(s + i);
    ushort4 o;
    o.x = f2bf(v.x); o.y = f2bf(v.y); o.z = f2bf(v.z); o.w = f2bf(v.w);
    *(ushort4*)(d + i) = o;
}

// ---------------- GEMM (m97 structure, round-10 proven) --------------------
// MODE 0: f32 out to C0 (bias b0).  MODE 2: QKV fused — n-seg 0 -> Q (scaled
// by QSCALE), 1 -> K, 2 -> V^T (transposed write [b,h,d,seq]).
template <int MODE>
__global__ __launch_bounds__(256, 2)
void gemm_bt(const unsigned short* __restrict__ A,
             const unsigned short* __restrict__ Bw,
             const float* __restrict__ b0, const float* __restrict__ b1,
             const float* __restrict__ b2,
             void* __restrict__ C0, void* __restrict__ C1, void* __restrict__ C2,
             int M, int N, int Kd) {
    __shared__ unsigned short As[128][64];
    __shared__ unsigned short Bs[128][64];

    const int t    = threadIdx.x;
    const int lane = t & 63;
    const int wid  = t >> 6;
    const int g    = lane >> 4;
    const int lr   = lane & 15;
    const int wm   = wid >> 1, wn = wid & 1;
    const int m0   = blockIdx.x * 128, n0 = blockIdx.y * 128;
    const int srow = lane >> 3;          // 0..7 within 8-row stripe
    const int scol = (lane & 7) * 8;     // shorts

    f32x4 acc[4][4];
    const f32x4 zero = {0.f, 0.f, 0.f, 0.f};
#pragma unroll
    for (int i = 0; i < 4; ++i)
#pragma unroll
        for (int j = 0; j < 4; ++j) acc[i][j] = zero;

    for (int kt = 0; kt < Kd; kt += 64) {
#pragma unroll
        for (int p = 0; p < 4; ++p) {
            int rowA = wid * 32 + p * 8;
            gload16(&As[rowA][0], A  + (size_t)(m0 + rowA + srow) * Kd + kt + scol);
            gload16(&Bs[rowA][0], Bw + (size_t)(n0 + rowA + srow) * Kd + kt + scol);
        }
        __syncthreads();   // compiler drains vmcnt before barrier
#pragma unroll
        for (int ks = 0; ks < 2; ++ks) {
            bf16x8 af[4], bfr[4];
#pragma unroll
            for (int m = 0; m < 4; ++m)
                af[m] = *(const bf16x8*)&As[wm * 64 + m * 16 + lr][ks * 32 + g * 8];
#pragma unroll
            for (int n = 0; n < 4; ++n)
                bfr[n] = *(const bf16x8*)&Bs[wn * 64 + n * 16 + lr][ks * 32 + g * 8];
#pragma unroll
            for (int m = 0; m < 4; ++m)
#pragma unroll
                for (int n = 0; n < 4; ++n)
                    acc[m][n] = __builtin_amdgcn_mfma_f32_16x16x32_bf16(af[m], bfr[n], acc[m][n], 0, 0, 0);
        }
        __syncthreads();
    }

    int seg = MODE == 2 ? (n0 >> 10) : 0;
    if (MODE == 2 && seg == 2) {
        // V^T write: [b*1024 + colL][seq], 4 consecutive seq per ushort4
        unsigned short* CwT = (unsigned short*)C2;
        int nl = n0 & 1023;
#pragma unroll
        for (int n = 0; n < 4; ++n) {
            int colL = nl + wn * 64 + n * 16 + lr;
            float bv = b2[colL];
#pragma unroll
            for (int m = 0; m < 4; ++m) {
                int rowg = m0 + wm * 64 + m * 16 + g * 4;
                int bb = rowg >> 11, seq = rowg & 2047;
                ushort4 w;
                w.x = f2bf(acc[m][n][0] + bv);
                w.y = f2bf(acc[m][n][1] + bv);
                w.z = f2bf(acc[m][n][2] + bv);
                w.w = f2bf(acc[m][n][3] + bv);
                *(ushort4*)(CwT + ((size_t)(bb * 1024 + colL)) * SEQ + seq) = w;
            }
        }
        return;
    }

    const float* bias;
    unsigned short* Cw = nullptr;
    float* Cf = nullptr;
    float scl = 1.0f;
    int nl;
    if (MODE == 2) {
        bias = seg == 0 ? b0 : b1;
        Cw = (unsigned short*)(seg == 0 ? C0 : C1);
        scl = seg == 0 ? QSCALE : 1.0f;
        nl = n0 & 1023;
    } else {
        bias = b0; Cf = (float*)C0; nl = n0;
    }
#pragma unroll
    for (int n = 0; n < 4; ++n) {
        int colL = nl + wn * 64 + n * 16 + lr;
        float bv = bias[colL];
#pragma unroll
        for (int m = 0; m < 4; ++m) {
            int rowg = m0 + wm * 64 + m * 16 + g * 4;
#pragma unroll
            for (int r = 0; r < 4; ++r) {
                float val = (acc[m][n][r] + bv) * scl;
                if (MODE == 2)
                    Cw[(size_t)(rowg + r) * EMB + colL] = f2bf(val);
                else
                    Cf[(size_t)(rowg + r) * EMB + colL] = val;
            }
        }
    }
}

// ---------------- Flash attention v8 (round-8 proven, best: 94.2 us) -------
// Q pre-scaled by 0.125*log2e -> scores are base-2 logits. V comes in as V^T.
// grid: 512 blocks (XCD-swizzled); block 512 = 8 waves; wave = 32 q-rows.
__global__ __launch_bounds__(512, 4)
void flash_attn(const unsigned short* __restrict__ Q,
                const unsigned short* __restrict__ K,
                const unsigned short* __restrict__ VT,
                unsigned short* __restrict__ O) {
    __shared__ unsigned char KsB[2][64 * 128];   // K[k][d],  XOR-16B swizzled
    __shared__ unsigned char VtB[2][64 * 128];   // V^T[d][k], XOR-16B swizzled

    // bijective XCD swizzle: 512 blocks, 8 XCDs, 64 consecutive per XCD
    const int nwg  = gridDim.x * gridDim.y * gridDim.z;
    const int cpx  = nwg >> 3;
    const int bid0 = (blockIdx.z * gridDim.y + blockIdx.y) * gridDim.x + blockIdx.x;
    const int bid  = (bid0 % 8) * cpx + (bid0 / 8);
    const int bx   = bid & (gridDim.x - 1);          // SEQ/256 = 8 (pow2)
    const int h    = (bid >> 3) & 15;
    const int b    = bid >> 7;

    const int t    = threadIdx.x;
    const int wid  = t >> 6;
    const int lane = t & 63;
    const int l31  = lane & 31;
    const int hi   = lane >> 5;
    const int hi16 = hi << 4;
    const int sw   = (l31 & 7) << 4;
    const int qbase = bx * 256 + wid * 32;
    const size_t rowbase = (size_t)b * SEQ;
    const unsigned short* Kh  = K + rowbase * EMB + h * HD;
    const unsigned short* Vth = VT + (size_t)(b * 1024 + h * HD) * SEQ;

    // staging geometry: slot t stages 16B; LDS linear, source pre-swizzled
    const int grow = t >> 3;                         // K row / V^T d-row
    const int gc16 = (t & 7) ^ (grow & 7);           // XOR moved to source
    const unsigned short* Ksrc0 = Kh  + (size_t)grow * EMB + gc16 * 8;
    const unsigned short* Vsrc0 = Vth + (size_t)grow * SEQ + gc16 * 8;

    bf16x8 qf[4];
#pragma unroll
    for (int db = 0; db < 4; ++db)
        qf[db] = *(const bf16x8*)(Q + (rowbase + qbase + l31) * EMB + h * HD + db * 16 + hi * 8);

    // all-ones B fragment: P x ones MFMA = softmax denominator in C-layout
    bf16x8 vones;
#pragma unroll
    for (int j = 0; j < 8; ++j) vones[j] = (__bf16)1.0f;

    f32x16 o0, o1, o2;
#pragma unroll
    for (int r = 0; r < 16; ++r) { o0[r] = 0.f; o1[r] = 0.f; o2[r] = 0.f; }
    float me = -1e30f;

    auto issue_tile = [&](int kt) {
        unsigned char* Ks = KsB[kt & 1] + wid * 1024;   // wave-uniform base
        unsigned char* Vt = VtB[kt & 1] + wid * 1024;
        gload16(Ks, Ksrc0 + (size_t)kt * 64 * EMB);     // K rows advance by kt*64
        gload16(Vt, Vsrc0 + kt * 64);                   // V^T cols advance by kt*64
    };
    issue_tile(0);

    for (int kt = 0; kt < NT; ++kt) {
        unsigned char* Ks = KsB[kt & 1];
        unsigned char* Vt = VtB[kt & 1];

        __syncthreads();                      // drains DMA for tile kt; prev reads done

        if (kt + 1 < NT) issue_tile(kt + 1);  // DMA next tile into other buffer

        // S^T = K * Q^T : lane holds 32 k-scores for q = lane&31 (base-2 logits)
        f32x16 s0, s1;
#pragma unroll
        for (int r = 0; r < 16; ++r) { s0[r] = 0.f; s1[r] = 0.f; }
        __builtin_amdgcn_s_setprio(1);
#pragma unroll
        for (int db = 0; db < 4; ++db) {
            bf16x8 kf0 = *(const bf16x8*)(Ks + l31 * 128        + ((db * 32 + hi16) ^ sw));
            bf16x8 kf1 = *(const bf16x8*)(Ks + (l31 + 32) * 128 + ((db * 32 + hi16) ^ sw));
            s0 = __builtin_amdgcn_mfma_f32_32x32x16_bf16(kf0, qf[db], s0, 0, 0, 0);
            s1 = __builtin_amdgcn_mfma_f32_32x32x16_bf16(kf1, qf[db], s1, 0, 0, 0);
        }
        __builtin_amdgcn_s_setprio(0);

        // row max (max3-friendly nesting)
        float pm = fmaxf(fmaxf(s0[0], s0[1]), s0[2]);
#pragma unroll
        for (int r = 3; r < 15; r += 2) pm = fmaxf(fmaxf(pm, s0[r]), s0[r + 1]);
        pm = fmaxf(pm, s0[15]);
#pragma unroll
        for (int r = 0; r < 16; r += 2) pm = fmaxf(fmaxf(pm, s1[r]), s1[r + 1]);
        pm = fmaxf(pm, __shfl_xor(pm, 32));

        // defer-max: only rescale when max grew by > 8 (P bounded by 2^8)
        if (!__all(pm - me <= 8.0f)) {
            float mn = fmaxf(me, pm);
            float al = exp2v(me - mn);
            me = mn;
#pragma unroll
            for (int r = 0; r < 16; ++r) {
                int addr = hi16 + (((r & 3) + 8 * (r >> 2)) << 2);
                float ar = __int_as_float(
                    __builtin_amdgcn_ds_bpermute(addr, __float_as_int(al)));
                o0[r] *= ar; o1[r] *= ar; o2[r] *= ar;
            }
        }

        // exp2 (packed subtract; row-sum is MFMA'd below)
        s0 = s0 - me;
        s1 = s1 - me;
#pragma unroll
        for (int r = 0; r < 16; ++r) s0[r] = exp2v(s0[r]);
#pragma unroll
        for (int r = 0; r < 16; ++r) s1[r] = exp2v(s1[r]);

        // pack P -> bf16 A-fragments via cvt_pk + permlane32_swap
        bf16x8 pa[4];
#pragma unroll
        for (int kb = 0; kb < 2; ++kb) {
            uint32_t dw[8];
#pragma unroll
            for (int i = 0; i < 8; ++i)
                dw[i] = kb == 0 ? cvtpk(s0[2 * i], s0[2 * i + 1])
                                : cvtpk(s1[2 * i], s1[2 * i + 1]);
            plswap(dw[0], dw[2]); plswap(dw[1], dw[3]);
            plswap(dw[4], dw[6]); plswap(dw[5], dw[7]);
            u32x4 w0 = {dw[0], dw[1], dw[2], dw[3]};
            u32x4 w1 = {dw[4], dw[5], dw[6], dw[7]};
            pa[kb * 2]     = __builtin_bit_cast(bf16x8, w0);
            pa[kb * 2 + 1] = __builtin_bit_cast(bf16x8, w1);
        }

        // PV + row-sum (P x ones)
        __builtin_amdgcn_s_setprio(1);
#pragma unroll
        for (int kk = 0; kk < 4; ++kk) {
            bf16x8 vf0 = *(const bf16x8*)(Vt + l31 * 128        + ((kk * 32 + hi16) ^ sw));
            bf16x8 vf1 = *(const bf16x8*)(Vt + (l31 + 32) * 128 + ((kk * 32 + hi16) ^ sw));
            o0 = __builtin_amdgcn_mfma_f32_32x32x16_bf16(pa[kk], vf0, o0, 0, 0, 0);
            o1 = __builtin_amdgcn_mfma_f32_32x32x16_bf16(pa[kk], vf1, o1, 0, 0, 0);
            o2 = __builtin_amdgcn_mfma_f32_32x32x16_bf16(pa[kk], vones, o2, 0, 0, 0);
        }
        __builtin_amdgcn_s_setprio(0);
    }

    // epilogue: o2[r] holds the softmax denominator for this lane's q-row
#pragma unroll
    for (int r = 0; r < 16; ++r) {
        float inv = 1.0f / o2[r];
        int q = qbase + (r & 3) + 8 * (r >> 2) + 4 * hi;
        size_t ro = (rowbase + q) * EMB + h * HD;
        O[ro + l31]      = f2bf(o0[r] * inv);
        O[ro + 32 + l31] = f2bf(o1[r] * inv);
    }
}

extern "C" void kernel_launch(void* const* d_in, const int* in_sizes, int n_in,
                              void* d_out, int out_size, void* d_ws, size_t ws_size,
                              hipStream_t stream) {
    const float* x  = (const float*)d_in[0];
    const float* wq = (const float*)d_in[1];
    const float* bq = (const float*)d_in[2];
    const float* wk = (const float*)d_in[3];
    const float* bk = (const float*)d_in[4];
    const float* wv = (const float*)d_in[5];
    const float* bv = (const float*)d_in[6];
    const float* wo = (const float*)d_in[7];
    const float* bo = (const float*)d_in[8];

    char* ws = (char*)d_ws;
    const size_t M = (size_t)BSZ * SEQ;              // 8192
    unsigned short* xb    = (unsigned short*)ws;                       // 16 MB, reused as attn out
    unsigned short* wqkvb = (unsigned short*)(ws + (size_t)16 * 1024 * 1024);  // 6 MB
    unsigned short* wob   = (unsigned short*)(ws + (size_t)22 * 1024 * 1024);  // 2 MB
    unsigned short* Qb    = (unsigned short*)(ws + (size_t)24 * 1024 * 1024);
    unsigned short* Kb    = Qb + M * EMB;
    unsigned short* VTb   = Kb + M * EMB;            // V^T [b*16+h][64][2048]

    const int nX = (int)(M * EMB);
    cast_kernel<<<nX / 1024, 256, 0, stream>>>(x, xb, nX);
    cast4_kernel<<<dim3(1024, 4), 256, 0, stream>>>(
        wq, wk, wv, wo,
        wqkvb, wqkvb + 1024 * 1024, wqkvb + 2 * 1024 * 1024, wob);

    gemm_bt<2><<<dim3(64, 24), 256, 0, stream>>>(xb, wqkvb, bq, bk, bv,
                                                 Qb, Kb, VTb, (int)M, 3 * EMB, EMB);

    flash_attn<<<dim3(SEQ / 256, NH, BSZ), 512, 0, stream>>>(Qb, Kb, VTb, xb);

    gemm_bt<0><<<dim3(64, 8), 256, 0, stream>>>(xb, wob, bo, nullptr, nullptr,
                                                d_out, nullptr, nullptr, (int)M, EMB, EMB);
}